// Round 6
// baseline (65.016 us; speedup 1.0000x reference)
//
#include <hip/hip_runtime.h>
#include <hip/hip_bf16.h>

#define H 768
#define K2P 1600          // 768 + 768 + 64 (width 30 padded to 64)
#define SEQLEN 512
#define NSPAN 128

typedef __attribute__((ext_vector_type(8))) short s16x8;
typedef __attribute__((ext_vector_type(4))) float f32x4;

#define MFMA_BF16 __builtin_amdgcn_mfma_f32_16x16x32_bf16

__device__ __forceinline__ short f2bf(float f) {
    __hip_bfloat16 h = __float2bfloat16(f);
    return *reinterpret_cast<short*>(&h);
}
__device__ __forceinline__ float bf2f(short s) {
    unsigned int u = ((unsigned int)(unsigned short)s) << 16;
    return __builtin_bit_cast(float, u);
}

// ---------------------------------------------------------------------------
// Barrier-free per-wave 32x32 GEMM tile, bf16 inputs from global memory.
// 4 named prefetch stages (2 x 64-K iterations of lookahead) keep 8-16 loads
// in flight; no LDS, no barriers -> race-free by construction (rule #20:
// all stage registers are named scalars, statically indexed).
// ---------------------------------------------------------------------------
#define LDST(S, KO)                                                            \
    S##a0 = *(const s16x8*)(pA0 + (KO));                                       \
    S##a1 = *(const s16x8*)(pA1 + (KO));                                       \
    S##b0 = *(const s16x8*)(pB0 + (KO));                                       \
    S##b1 = *(const s16x8*)(pB1 + (KO));

#define MMST(S)                                                                \
    acc00 = MFMA_BF16(S##a0, S##b0, acc00, 0, 0, 0);                           \
    acc01 = MFMA_BF16(S##a0, S##b1, acc01, 0, 0, 0);                           \
    acc10 = MFMA_BF16(S##a1, S##b0, acc10, 0, 0, 0);                           \
    acc11 = MFMA_BF16(S##a1, S##b1, acc11, 0, 0, 0);

__device__ __forceinline__ void gemm32(
    const short* __restrict__ A, int ldA, int am0,
    const short* __restrict__ Wt, int ldW, int n0,
    int K, int l,
    f32x4& acc00, f32x4& acc01, f32x4& acc10, f32x4& acc11)
{
    const int lr = l & 15, lg = l >> 4;
    const short* pA0 = A + (size_t)(am0 + lr) * ldA + lg * 8;
    const short* pA1 = A + (size_t)(am0 + 16 + lr) * ldA + lg * 8;
    const short* pB0 = Wt + (size_t)(n0 + lr) * ldW + lg * 8;
    const short* pB1 = Wt + (size_t)(n0 + 16 + lr) * ldW + lg * 8;

    s16x8 S0a0, S0a1, S0b0, S0b1;   // k = 64i
    s16x8 S1a0, S1a1, S1b0, S1b1;   // k = 64i + 32
    s16x8 S2a0, S2a1, S2b0, S2b1;   // k = 64(i+1)
    s16x8 S3a0, S3a1, S3b0, S3b1;   // k = 64(i+1) + 32

    const int iters = K >> 6;       // 12 (K=768) or 25 (K=1600), always >= 4
    LDST(S0, 0) LDST(S1, 32) LDST(S2, 64) LDST(S3, 96)

    for (int i = 0; i < iters; i += 2) {
        MMST(S0)
        if (i + 2 < iters) { LDST(S0, 64*(i+2)) }
        MMST(S1)
        if (i + 2 < iters) { LDST(S1, 64*(i+2) + 32) }
        if (i + 1 < iters) {
            MMST(S2)
            if (i + 3 < iters) { LDST(S2, 64*(i+3)) }
            MMST(S3)
            if (i + 3 < iters) { LDST(S3, 64*(i+3) + 32) }
        }
    }
}

// ---------------------------------------------------------------------------
// P0: weight transposes -> bf16 [n][k]; gather seq -> Xg bf16; Xcat width cols.
// ---------------------------------------------------------------------------
__global__ __launch_bounds__(256) void k_prep(
    const float* __restrict__ seq,
    const int* __restrict__ starts, const int* __restrict__ ends,
    const float* __restrict__ Ws, const float* __restrict__ We,
    const float* __restrict__ W1, const float* __restrict__ Wout,
    const float* __restrict__ wemb,
    short* __restrict__ WtSE, short* __restrict__ WtAB,
    short* __restrict__ WtOut, short* __restrict__ Xg, short* __restrict__ Xcat)
{
    const int b = blockIdx.x;
    const int tid = threadIdx.x;

    if (b < 2304) {                       // Ws/We/Wa+Wc/Wb-Wc transposes
        const int sec = b / 576;
        const int t = b % 576;
        const int kt = t / 24, nt = t % 24;
        __shared__ float tile[32][33];
        const int kk = tid >> 3;
        const int c4 = (tid & 7) << 2;
        const int srow = kt * 32 + kk, scol = nt * 32 + c4;
        float4 v;
        if (sec == 0)      v = *(const float4*)(Ws + (size_t)srow * H + scol);
        else if (sec == 1) v = *(const float4*)(We + (size_t)srow * H + scol);
        else {
            const float* base = W1 + (size_t)(sec == 2 ? 0 : H) * H;
            float4 u = *(const float4*)(base + (size_t)srow * H + scol);
            float4 c = *(const float4*)(W1 + (size_t)2*H*H + (size_t)srow * H + scol);
            const float sg = (sec == 2) ? 1.f : -1.f;
            v = make_float4(fmaf(sg,c.x,u.x), fmaf(sg,c.y,u.y),
                            fmaf(sg,c.z,u.z), fmaf(sg,c.w,u.w));
        }
        tile[kk][c4+0]=v.x; tile[kk][c4+1]=v.y; tile[kk][c4+2]=v.z; tile[kk][c4+3]=v.w;
        __syncthreads();
        short* dst = (sec < 2 ? WtSE : WtAB) + (size_t)(sec & 1) * H * H;
        const int nn = tid >> 3;
        short4 o;
        o.x = f2bf(tile[c4+0][nn]); o.y = f2bf(tile[c4+1][nn]);
        o.z = f2bf(tile[c4+2][nn]); o.w = f2bf(tile[c4+3][nn]);
        *(short4*)(dst + (size_t)(nt*32 + nn) * H + kt*32 + c4) = o;
    } else if (b < 3504) {                // Wout^T -> [768][1600], zero-padded
        const int t = b - 2304;
        const int nt = t / 50, kt = t % 50;
        __shared__ float tile[32][33];
        const int kk = tid >> 3;
        const int c4 = (tid & 7) << 2;
        const int srow = kt * 32 + kk, scol = nt * 32 + c4;
        float4 v = make_float4(0.f, 0.f, 0.f, 0.f);
        if (srow < 1566) v = *(const float4*)(Wout + (size_t)srow * H + scol);
        tile[kk][c4+0]=v.x; tile[kk][c4+1]=v.y; tile[kk][c4+2]=v.z; tile[kk][c4+3]=v.w;
        __syncthreads();
        const int nn = tid >> 3;
        short4 o;
        o.x = f2bf(tile[c4+0][nn]); o.y = f2bf(tile[c4+1][nn]);
        o.z = f2bf(tile[c4+2][nn]); o.w = f2bf(tile[c4+3][nn]);
        *(short4*)(WtOut + (size_t)(nt*32 + nn) * K2P + kt*32 + c4) = o;
    } else if (b < 3760) {                // gather: Xg[0:512)=starts, [512:1024)=ends
        const int gr = (b - 3504) * 4 + (tid >> 6);
        const int c = tid & 63;
        const int spanrow = gr & 511;
        const int idx = (gr < 512) ? starts[spanrow] : ends[spanrow];
        const size_t base = ((size_t)(spanrow >> 7) * SEQLEN + idx) * H;
        #pragma unroll
        for (int i = 0; i < 12; ++i) {
            const int col = c + i*64;
            Xg[(size_t)gr * H + col] = f2bf(seq[base + col]);
        }
    } else {                              // Xcat width-emb cols 1536..1599
        const int t = (b - 3760) * 256 + tid;
        const int row = t >> 6, c = t & 63;
        int wd = ends[row] - starts[row];
        wd = wd < 0 ? 0 : (wd > 10 ? 10 : wd);
        Xcat[(size_t)row * K2P + 1536 + c] = (c < 30) ? f2bf(wemb[wd*30 + c]) : (short)0;
    }
}

// ---------------------------------------------------------------------------
// G1: Xcat[:, gc] = Xg(half) @ WtSE^T + bias   (N = 1536 over both halves)
// One wave per block, 32x32 tile, barrier-free.
// ---------------------------------------------------------------------------
__global__ __launch_bounds__(64) void k_g1(
    const short* __restrict__ Xg, const short* __restrict__ WtSE,
    const float* __restrict__ bs, const float* __restrict__ be,
    short* __restrict__ Xcat)
{
    const int l = threadIdx.x;
    const int bm = blockIdx.x, n0 = blockIdx.y * 32;
    const int am0 = (n0 >= 768 ? 512 : 0) + bm * 32;

    f32x4 acc00 = {}, acc01 = {}, acc10 = {}, acc11 = {};
    gemm32(Xg, H, am0, WtSE, H, n0, H, l, acc00, acc01, acc10, acc11);

    const int lr = l & 15, lg = l >> 4;
    const int gc0 = n0 + lr, gc1 = n0 + 16 + lr;
    const float bv0 = (gc0 < 768) ? bs[gc0] : be[gc0 - 768];
    const float bv1 = (gc1 < 768) ? bs[gc1] : be[gc1 - 768];
    const int r0 = bm*32 + lg*4, r1 = r0 + 16;
    #pragma unroll
    for (int rg = 0; rg < 4; ++rg) {
        Xcat[(size_t)(r0 + rg) * K2P + gc0] = f2bf(acc00[rg] + bv0);
        Xcat[(size_t)(r0 + rg) * K2P + gc1] = f2bf(acc01[rg] + bv1);
        Xcat[(size_t)(r1 + rg) * K2P + gc0] = f2bf(acc10[rg] + bv0);
        Xcat[(size_t)(r1 + rg) * K2P + gc1] = f2bf(acc11[rg] + bv1);
    }
}

// ---------------------------------------------------------------------------
// G2: SR = Xcat(K=1600) @ WtOut^T + b_out
// ---------------------------------------------------------------------------
__global__ __launch_bounds__(64) void k_g2(
    const short* __restrict__ Xcat, const short* __restrict__ WtOut,
    const float* __restrict__ bout, short* __restrict__ SR)
{
    const int l = threadIdx.x;
    const int bm = blockIdx.x, n0 = blockIdx.y * 32;

    f32x4 acc00 = {}, acc01 = {}, acc10 = {}, acc11 = {};
    gemm32(Xcat, K2P, bm*32, WtOut, K2P, n0, K2P, l, acc00, acc01, acc10, acc11);

    const int lr = l & 15, lg = l >> 4;
    const int gc0 = n0 + lr, gc1 = n0 + 16 + lr;
    const float bv0 = bout[gc0], bv1 = bout[gc1];
    const int r0 = bm*32 + lg*4, r1 = r0 + 16;
    #pragma unroll
    for (int rg = 0; rg < 4; ++rg) {
        SR[(size_t)(r0 + rg) * H + gc0] = f2bf(acc00[rg] + bv0);
        SR[(size_t)(r0 + rg) * H + gc1] = f2bf(acc01[rg] + bv1);
        SR[(size_t)(r1 + rg) * H + gc0] = f2bf(acc10[rg] + bv0);
        SR[(size_t)(r1 + rg) * H + gc1] = f2bf(acc11[rg] + bv1);
    }
}

// ---------------------------------------------------------------------------
// G3: y<48: AB[:, gc] = SR @ WtAB^T (+b1 for cols<768)   [fp32 out]
//     y==48: mention = SR @ Wm + b_ment
// ---------------------------------------------------------------------------
__global__ __launch_bounds__(64) void k_g3(
    const short* __restrict__ SR, const short* __restrict__ WtAB,
    const float* __restrict__ b1, const float* __restrict__ Wm,
    const float* __restrict__ bment,
    float* __restrict__ AB, float* __restrict__ mention)
{
    const int l = threadIdx.x;
    const int bm = blockIdx.x;

    if (blockIdx.y == 48) {               // mention scores, 32 rows per block
        const float bm_add = bment[0];
        for (int rr = 0; rr < 32; ++rr) {
            const int row = bm*32 + rr;
            float p = 0.f;
            #pragma unroll
            for (int kk = 0; kk < 12; ++kk) {
                const int k = kk*64 + l;
                p = fmaf(bf2f(SR[(size_t)row * H + k]), Wm[k], p);
            }
            #pragma unroll
            for (int off = 32; off; off >>= 1) p += __shfl_down(p, off);
            if (l == 0) mention[row] = p + bm_add;
        }
        return;
    }

    const int n0 = blockIdx.y * 32;
    f32x4 acc00 = {}, acc01 = {}, acc10 = {}, acc11 = {};
    gemm32(SR, H, bm*32, WtAB, H, n0, H, l, acc00, acc01, acc10, acc11);

    const int lr = l & 15, lg = l >> 4;
    const int gc0 = n0 + lr, gc1 = n0 + 16 + lr;
    const float bv0 = (gc0 < 768) ? b1[gc0] : 0.f;
    const float bv1 = (gc1 < 768) ? b1[gc1] : 0.f;
    const int r0 = bm*32 + lg*4, r1 = r0 + 16;
    #pragma unroll
    for (int rg = 0; rg < 4; ++rg) {
        AB[(size_t)(r0 + rg) * 1536 + gc0] = acc00[rg] + bv0;
        AB[(size_t)(r0 + rg) * 1536 + gc1] = acc01[rg] + bv1;
        AB[(size_t)(r1 + rg) * 1536 + gc0] = acc10[rg] + bv0;
        AB[(size_t)(r1 + rg) * 1536 + gc1] = acc11[rg] + bv1;
    }
}

// ---------------------------------------------------------------------------
// G4: pair[b,i,j] = (j<i) ? sum_h relu(AI+BJ)*W2[h] + b2 : 0
// Full 8x8 tile grid; upper tiles write zeros (no memset needed).
// Register-prefetch of next chunk overlaps global latency with compute.
// AB = [512][1536] fp32, AI at +0 (b1 folded), BJ at +768.
// ---------------------------------------------------------------------------
__global__ __launch_bounds__(256) void k_pair(
    const float* __restrict__ AB, const float* __restrict__ W2,
    const float* __restrict__ b2, float* __restrict__ pair)
{
    const int tid = threadIdx.x;
    const int bx = blockIdx.x & 7, by = blockIdx.x >> 3;
    const int bz = blockIdx.y;

    const int tx = tid & 15, ty = tid >> 4;
    const int i = by * 16 + ty, j = bx * 16 + tx;
    float* outp = pair + ((size_t)bz * NSPAN + i) * NSPAN + j;

    if (bx > by) { *outp = 0.f; return; }   // strictly-upper tile: all zero

    __shared__ __align__(16) float Ais[16][68];
    __shared__ __align__(16) float Bjs[16][68];
    __shared__ __align__(16) float w2s[768];
    for (int q = tid; q < 768; q += 256) w2s[q] = W2[q];

    const int sr = tid >> 4, sc = (tid & 15) << 2;
    const float* aSrc = AB + ((size_t)bz*NSPAN + by*16 + sr)*1536 + sc;
    const float* bSrc = AB + ((size_t)bz*NSPAN + bx*16 + sr)*1536 + 768 + sc;
    float acc = 0.f;

    float4 ra = *(const float4*)(aSrc);
    float4 rb = *(const float4*)(bSrc);

    for (int ch = 0; ch < 12; ++ch) {
        __syncthreads();
        *(float4*)&Ais[sr][sc] = ra;
        *(float4*)&Bjs[sr][sc] = rb;
        __syncthreads();
        if (ch < 11) {                       // next-chunk loads hide under FMAs
            ra = *(const float4*)(aSrc + (ch+1)*64);
            rb = *(const float4*)(bSrc + (ch+1)*64);
        }
        #pragma unroll
        for (int hq = 0; hq < 16; ++hq) {
            float4 a = *(const float4*)&Ais[ty][hq << 2];
            float4 b = *(const float4*)&Bjs[tx][hq << 2];
            float4 wv = *(const float4*)&w2s[ch*64 + (hq << 2)];
            acc = fmaf(fmaxf(a.x + b.x, 0.f), wv.x, acc);
            acc = fmaf(fmaxf(a.y + b.y, 0.f), wv.y, acc);
            acc = fmaf(fmaxf(a.z + b.z, 0.f), wv.z, acc);
            acc = fmaf(fmaxf(a.w + b.w, 0.f), wv.w, acc);
        }
    }
    *outp = (j < i) ? (acc + b2[0]) : 0.f;
}

// ---------------------------------------------------------------------------
extern "C" void kernel_launch(void* const* d_in, const int* in_sizes, int n_in,
                              void* d_out, int out_size, void* d_ws, size_t ws_size,
                              hipStream_t stream)
{
    const float* seq    = (const float*)d_in[0];
    const int*   starts = (const int*)  d_in[1];
    const int*   ends   = (const int*)  d_in[2];
    const float* Ws     = (const float*)d_in[3];
    const float* bs     = (const float*)d_in[4];
    const float* We     = (const float*)d_in[5];
    const float* be     = (const float*)d_in[6];
    const float* wemb   = (const float*)d_in[7];
    const float* Wout   = (const float*)d_in[8];
    const float* bout   = (const float*)d_in[9];
    const float* Wm     = (const float*)d_in[10];
    const float* bment  = (const float*)d_in[11];
    const float* W1     = (const float*)d_in[12];
    const float* b1     = (const float*)d_in[13];
    const float* W2     = (const float*)d_in[14];
    const float* b2     = (const float*)d_in[15];

    float* ws = (float*)d_ws;
    float* AB    = ws;                          // 512*1536 fp32
    short* Xg    = (short*)(ws + 786432);       // 1024*768 bf16
    short* Xcat  = (short*)(ws + 1179648);      // 512*1600 bf16
    short* SR    = (short*)(ws + 1589248);      // 512*768  bf16
    short* WtSE  = (short*)(ws + 1785856);      // 1536*768 bf16
    short* WtAB  = (short*)(ws + 2375680);      // 1536*768 bf16
    short* WtOut = (short*)(ws + 2965504);      // 768*1600 bf16

    float* out_mention = (float*)d_out;         // 512
    float* out_pair    = (float*)d_out + 512;   // 4*128*128

    hipLaunchKernelGGL(k_prep, dim3(3888), dim3(256), 0, stream,
                       seq, starts, ends, Ws, We, W1, Wout, wemb,
                       WtSE, WtAB, WtOut, Xg, Xcat);
    hipLaunchKernelGGL(k_g1, dim3(16, 48), dim3(64), 0, stream,
                       Xg, WtSE, bs, be, Xcat);
    hipLaunchKernelGGL(k_g2, dim3(16, 24), dim3(64), 0, stream,
                       Xcat, WtOut, bout, SR);
    hipLaunchKernelGGL(k_g3, dim3(16, 49), dim3(64), 0, stream,
                       SR, WtAB, b1, Wm, bment, AB, out_mention);
    hipLaunchKernelGGL(k_pair, dim3(64, 4), dim3(256), 0, stream,
                       AB, W2, b2, out_pair);
}

// Round 7
// 47.641 us; speedup vs baseline: 1.3647x; 1.3647x over previous
//
#include <hip/hip_runtime.h>
#include <hip/hip_bf16.h>

#define H 768
#define K2P 1600          // 768 + 768 + 64 (width 30 padded to 64)
#define SEQLEN 512
#define NSPAN 128

typedef __attribute__((ext_vector_type(8))) short s16x8;
typedef __attribute__((ext_vector_type(4))) float f32x4;

#define MFMA_BF16 __builtin_amdgcn_mfma_f32_16x16x32_bf16

__device__ __forceinline__ short f2bf(float f) {
    __hip_bfloat16 h = __float2bfloat16(f);
    return *reinterpret_cast<short*>(&h);
}
__device__ __forceinline__ float bf2f(short s) {
    unsigned int u = ((unsigned int)(unsigned short)s) << 16;
    return __builtin_bit_cast(float, u);
}

// ---------------------------------------------------------------------------
// Reg-staged double-buffered GEMM pipeline (race-free: only __syncthreads +
// compiler-tracked data deps; no manual vmcnt counting — round-5 post-mortem).
// 128 threads (2 waves), 32x64 output tile, BK=64.
// Per step s: issue global loads (tile s+2) -> named reg set; compute tile s
// from LDS; ds_write reg set holding tile s+1 (loaded a FULL step earlier, so
// ~600cyc of compute covers its latency); one barrier.
// LDS layout per buffer: A rows 0..31 at bytes [0,4096), B rows 0..63 at
// [4096,12288); row = 128B, XOR-swizzled slots (slot ^ row&7) to keep the
// stride-128B ds_read_b128 fragment reads bank-conflict-free (T2/G4).
// ---------------------------------------------------------------------------
#define SLOAD(P, K0)                                                           \
    P##0 = *(const s16x8*)(sA0 + (K0));                                        \
    P##1 = *(const s16x8*)(sA1 + (K0));                                        \
    P##2 = *(const s16x8*)(sB0 + (K0));                                        \
    P##3 = *(const s16x8*)(sB1 + (K0));                                        \
    P##4 = *(const s16x8*)(sB2 + (K0));                                        \
    P##5 = *(const s16x8*)(sB3 + (K0));

#define SWRITE(P, BUF)                                                         \
    *(s16x8*)((char*)(BUF) + dA0) = P##0;                                      \
    *(s16x8*)((char*)(BUF) + dA1) = P##1;                                      \
    *(s16x8*)((char*)(BUF) + dB0) = P##2;                                      \
    *(s16x8*)((char*)(BUF) + dB1) = P##3;                                      \
    *(s16x8*)((char*)(BUF) + dB2) = P##4;                                      \
    *(s16x8*)((char*)(BUF) + dB3) = P##5;

// One BK=64 step: 8 ds_read_b128 (swizzled) + 8 MFMA. Wave w owns cols w*32..+31.
__device__ __forceinline__ void mfma_step(const short* lbuf, int w, int l,
                                          f32x4& acc00, f32x4& acc01,
                                          f32x4& acc10, f32x4& acc11)
{
    const int r = l & 15, hi = l >> 4;
    #pragma unroll
    for (int kc = 0; kc < 2; ++kc) {
        s16x8 av0, av1, bv0, bv1;
        {
            const int row0 = r;
            av0 = *(const s16x8*)((const char*)lbuf + row0*128 + ((kc*64 + hi*16) ^ ((row0 & 7) << 4)));
            const int row1 = 16 + r;
            av1 = *(const s16x8*)((const char*)lbuf + row1*128 + ((kc*64 + hi*16) ^ ((row1 & 7) << 4)));
            const int rowb0 = w*32 + r;
            bv0 = *(const s16x8*)((const char*)lbuf + 4096 + rowb0*128 + ((kc*64 + hi*16) ^ ((rowb0 & 7) << 4)));
            const int rowb1 = w*32 + 16 + r;
            bv1 = *(const s16x8*)((const char*)lbuf + 4096 + rowb1*128 + ((kc*64 + hi*16) ^ ((rowb1 & 7) << 4)));
        }
        acc00 = MFMA_BF16(av0, bv0, acc00, 0, 0, 0);
        acc01 = MFMA_BF16(av0, bv1, acc01, 0, 0, 0);
        acc10 = MFMA_BF16(av1, bv0, acc10, 0, 0, 0);
        acc11 = MFMA_BF16(av1, bv1, acc11, 0, 0, 0);
    }
}

#define GEMM_PIPE(APTR, LDA, AM0, WPTR, LDW, N0, NSTEPS)                       \
    f32x4 acc00 = {}, acc01 = {}, acc10 = {}, acc11 = {};                      \
    {                                                                          \
        const int rl = l >> 3, sl = l & 7;                                     \
        const int ra0 = w*16 + rl,      ra1 = w*16 + 8 + rl;                   \
        const int rb0 = w*32 + rl,      rb1 = w*32 + 8 + rl;                   \
        const int rb2 = w*32 + 16 + rl, rb3 = w*32 + 24 + rl;                  \
        const short* sA0 = (APTR) + (size_t)((AM0) + ra0) * (LDA) + ((sl ^ (ra0 & 7)) << 3); \
        const short* sA1 = (APTR) + (size_t)((AM0) + ra1) * (LDA) + ((sl ^ (ra1 & 7)) << 3); \
        const short* sB0 = (WPTR) + (size_t)((N0) + rb0) * (LDW) + ((sl ^ (rb0 & 7)) << 3); \
        const short* sB1 = (WPTR) + (size_t)((N0) + rb1) * (LDW) + ((sl ^ (rb1 & 7)) << 3); \
        const short* sB2 = (WPTR) + (size_t)((N0) + rb2) * (LDW) + ((sl ^ (rb2 & 7)) << 3); \
        const short* sB3 = (WPTR) + (size_t)((N0) + rb3) * (LDW) + ((sl ^ (rb3 & 7)) << 3); \
        const int dA0 = (w*16)*128 + l*16,          dA1 = (w*16 + 8)*128 + l*16;      \
        const int dB0 = 4096 + (w*32)*128 + l*16,   dB1 = 4096 + (w*32 + 8)*128 + l*16; \
        const int dB2 = 4096 + (w*32+16)*128 + l*16, dB3 = 4096 + (w*32+24)*128 + l*16; \
        s16x8 Pa0, Pa1, Pa2, Pa3, Pa4, Pa5;                                    \
        s16x8 Pb0, Pb1, Pb2, Pb3, Pb4, Pb5;                                    \
        SLOAD(Pa, 0)                                                           \
        SWRITE(Pa, lds[0])                                                     \
        SLOAD(Pa, 64)                                                          \
        __syncthreads();                                                       \
        for (int s = 0; s < (NSTEPS); s += 2) {                                \
            if (s + 2 < (NSTEPS)) { SLOAD(Pb, 64*(s+2)) }                      \
            mfma_step(lds[0], w, l, acc00, acc01, acc10, acc11);               \
            if (s + 1 < (NSTEPS)) { SWRITE(Pa, lds[1]) }                       \
            __syncthreads();                                                   \
            if (s + 1 < (NSTEPS)) {                                            \
                if (s + 3 < (NSTEPS)) { SLOAD(Pa, 64*(s+3)) }                  \
                mfma_step(lds[1], w, l, acc00, acc01, acc10, acc11);           \
                if (s + 2 < (NSTEPS)) { SWRITE(Pb, lds[0]) }                   \
                __syncthreads();                                               \
            }                                                                  \
        }                                                                      \
    }

// ---------------------------------------------------------------------------
// P0: weight transposes -> bf16 [n][k]; gather seq -> Xg bf16; Xcat width cols.
// ---------------------------------------------------------------------------
__global__ __launch_bounds__(256) void k_prep(
    const float* __restrict__ seq,
    const int* __restrict__ starts, const int* __restrict__ ends,
    const float* __restrict__ Ws, const float* __restrict__ We,
    const float* __restrict__ W1, const float* __restrict__ Wout,
    const float* __restrict__ wemb,
    short* __restrict__ WtSE, short* __restrict__ WtAB,
    short* __restrict__ WtOut, short* __restrict__ Xg, short* __restrict__ Xcat)
{
    const int b = blockIdx.x;
    const int tid = threadIdx.x;

    if (b < 2304) {                       // Ws/We/Wa+Wc/Wb-Wc transposes
        const int sec = b / 576;
        const int t = b % 576;
        const int kt = t / 24, nt = t % 24;
        __shared__ float tile[32][33];
        const int kk = tid >> 3;
        const int c4 = (tid & 7) << 2;
        const int srow = kt * 32 + kk, scol = nt * 32 + c4;
        float4 v;
        if (sec == 0)      v = *(const float4*)(Ws + (size_t)srow * H + scol);
        else if (sec == 1) v = *(const float4*)(We + (size_t)srow * H + scol);
        else {
            const float* base = W1 + (size_t)(sec == 2 ? 0 : H) * H;
            float4 u = *(const float4*)(base + (size_t)srow * H + scol);
            float4 c = *(const float4*)(W1 + (size_t)2*H*H + (size_t)srow * H + scol);
            const float sg = (sec == 2) ? 1.f : -1.f;
            v = make_float4(fmaf(sg,c.x,u.x), fmaf(sg,c.y,u.y),
                            fmaf(sg,c.z,u.z), fmaf(sg,c.w,u.w));
        }
        tile[kk][c4+0]=v.x; tile[kk][c4+1]=v.y; tile[kk][c4+2]=v.z; tile[kk][c4+3]=v.w;
        __syncthreads();
        short* dst = (sec < 2 ? WtSE : WtAB) + (size_t)(sec & 1) * H * H;
        const int nn = tid >> 3;
        short4 o;
        o.x = f2bf(tile[c4+0][nn]); o.y = f2bf(tile[c4+1][nn]);
        o.z = f2bf(tile[c4+2][nn]); o.w = f2bf(tile[c4+3][nn]);
        *(short4*)(dst + (size_t)(nt*32 + nn) * H + kt*32 + c4) = o;
    } else if (b < 3504) {                // Wout^T -> [768][1600], zero-padded
        const int t = b - 2304;
        const int nt = t / 50, kt = t % 50;
        __shared__ float tile[32][33];
        const int kk = tid >> 3;
        const int c4 = (tid & 7) << 2;
        const int srow = kt * 32 + kk, scol = nt * 32 + c4;
        float4 v = make_float4(0.f, 0.f, 0.f, 0.f);
        if (srow < 1566) v = *(const float4*)(Wout + (size_t)srow * H + scol);
        tile[kk][c4+0]=v.x; tile[kk][c4+1]=v.y; tile[kk][c4+2]=v.z; tile[kk][c4+3]=v.w;
        __syncthreads();
        const int nn = tid >> 3;
        short4 o;
        o.x = f2bf(tile[c4+0][nn]); o.y = f2bf(tile[c4+1][nn]);
        o.z = f2bf(tile[c4+2][nn]); o.w = f2bf(tile[c4+3][nn]);
        *(short4*)(WtOut + (size_t)(nt*32 + nn) * K2P + kt*32 + c4) = o;
    } else if (b < 3760) {                // gather: Xg[0:512)=starts, [512:1024)=ends
        const int gr = (b - 3504) * 4 + (tid >> 6);
        const int c = tid & 63;
        const int spanrow = gr & 511;
        const int idx = (gr < 512) ? starts[spanrow] : ends[spanrow];
        const size_t base = ((size_t)(spanrow >> 7) * SEQLEN + idx) * H;
        #pragma unroll
        for (int i = 0; i < 12; ++i) {
            const int col = c + i*64;
            Xg[(size_t)gr * H + col] = f2bf(seq[base + col]);
        }
    } else {                              // Xcat width-emb cols 1536..1599
        const int t = (b - 3760) * 256 + tid;
        const int row = t >> 6, c = t & 63;
        int wd = ends[row] - starts[row];
        wd = wd < 0 ? 0 : (wd > 10 ? 10 : wd);
        Xcat[(size_t)row * K2P + 1536 + c] = (c < 30) ? f2bf(wemb[wd*30 + c]) : (short)0;
    }
}

// ---------------------------------------------------------------------------
// G1: Xcat[:, gc] = Xg(half) @ WtSE^T + bias   (N = 1536 over both halves)
// ---------------------------------------------------------------------------
__global__ __launch_bounds__(128) void k_g1(
    const short* __restrict__ Xg, const short* __restrict__ WtSE,
    const float* __restrict__ bs, const float* __restrict__ be,
    short* __restrict__ Xcat)
{
    __shared__ __align__(16) short lds[2][6144];
    const int l = threadIdx.x & 63, w = threadIdx.x >> 6;
    const int bm = blockIdx.x, n0 = blockIdx.y * 64;
    const int am0 = (n0 >= 768 ? 512 : 0) + bm * 32;

    GEMM_PIPE(Xg, H, am0, WtSE, H, n0, 12)

    const int r = l & 15, hi = l >> 4;
    const int gc0 = n0 + w*32 + r, gc1 = gc0 + 16;
    const float bv0 = (gc0 < 768) ? bs[gc0] : be[gc0 - 768];
    const float bv1 = (gc1 < 768) ? bs[gc1] : be[gc1 - 768];
    const int r0 = bm*32 + hi*4, r1 = r0 + 16;
    #pragma unroll
    for (int rg = 0; rg < 4; ++rg) {
        Xcat[(size_t)(r0 + rg) * K2P + gc0] = f2bf(acc00[rg] + bv0);
        Xcat[(size_t)(r0 + rg) * K2P + gc1] = f2bf(acc01[rg] + bv1);
        Xcat[(size_t)(r1 + rg) * K2P + gc0] = f2bf(acc10[rg] + bv0);
        Xcat[(size_t)(r1 + rg) * K2P + gc1] = f2bf(acc11[rg] + bv1);
    }
}

// ---------------------------------------------------------------------------
// G2: SR = Xcat(K=1600) @ WtOut^T + b_out
// ---------------------------------------------------------------------------
__global__ __launch_bounds__(128) void k_g2(
    const short* __restrict__ Xcat, const short* __restrict__ WtOut,
    const float* __restrict__ bout, short* __restrict__ SR)
{
    __shared__ __align__(16) short lds[2][6144];
    const int l = threadIdx.x & 63, w = threadIdx.x >> 6;
    const int bm = blockIdx.x, n0 = blockIdx.y * 64;

    GEMM_PIPE(Xcat, K2P, bm*32, WtOut, K2P, n0, 25)

    const int r = l & 15, hi = l >> 4;
    const int gc0 = n0 + w*32 + r, gc1 = gc0 + 16;
    const float bv0 = bout[gc0], bv1 = bout[gc1];
    const int r0 = bm*32 + hi*4, r1 = r0 + 16;
    #pragma unroll
    for (int rg = 0; rg < 4; ++rg) {
        SR[(size_t)(r0 + rg) * H + gc0] = f2bf(acc00[rg] + bv0);
        SR[(size_t)(r0 + rg) * H + gc1] = f2bf(acc01[rg] + bv1);
        SR[(size_t)(r1 + rg) * H + gc0] = f2bf(acc10[rg] + bv0);
        SR[(size_t)(r1 + rg) * H + gc1] = f2bf(acc11[rg] + bv1);
    }
}

// ---------------------------------------------------------------------------
// G3: y<24: AB[:, gc] = SR @ WtAB^T (+b1 for cols<768)   [fp32 out]
//     y==24: mention = SR @ Wm + b_ment
// ---------------------------------------------------------------------------
__global__ __launch_bounds__(128) void k_g3(
    const short* __restrict__ SR, const short* __restrict__ WtAB,
    const float* __restrict__ b1, const float* __restrict__ Wm,
    const float* __restrict__ bment,
    float* __restrict__ AB, float* __restrict__ mention)
{
    const int l = threadIdx.x & 63, w = threadIdx.x >> 6;
    const int bm = blockIdx.x;

    if (blockIdx.y == 24) {               // mention scores, 32 rows per block
        const int rows0 = bm*32 + w*16;
        const float bm_add = bment[0];
        for (int rr = 0; rr < 16; ++rr) {
            const int row = rows0 + rr;
            float p = 0.f;
            #pragma unroll
            for (int kk = 0; kk < 12; ++kk) {
                const int k = kk*64 + l;
                p = fmaf(bf2f(SR[(size_t)row * H + k]), Wm[k], p);
            }
            #pragma unroll
            for (int off = 32; off; off >>= 1) p += __shfl_down(p, off);
            if (l == 0) mention[row] = p + bm_add;
        }
        return;
    }

    __shared__ __align__(16) short lds[2][6144];
    const int n0 = blockIdx.y * 64;

    GEMM_PIPE(SR, H, bm*32, WtAB, H, n0, 12)

    const int r = l & 15, hi = l >> 4;
    const int gc0 = n0 + w*32 + r, gc1 = gc0 + 16;
    const float bv0 = (gc0 < 768) ? b1[gc0] : 0.f;
    const float bv1 = (gc1 < 768) ? b1[gc1] : 0.f;
    const int r0 = bm*32 + hi*4, r1 = r0 + 16;
    #pragma unroll
    for (int rg = 0; rg < 4; ++rg) {
        AB[(size_t)(r0 + rg) * 1536 + gc0] = acc00[rg] + bv0;
        AB[(size_t)(r0 + rg) * 1536 + gc1] = acc01[rg] + bv1;
        AB[(size_t)(r1 + rg) * 1536 + gc0] = acc10[rg] + bv0;
        AB[(size_t)(r1 + rg) * 1536 + gc1] = acc11[rg] + bv1;
    }
}

// ---------------------------------------------------------------------------
// G4: pair[b,i,j] = (j<i) ? sum_h relu(AI+BJ)*W2[h] + b2 : 0
// Full 8x8 tile grid; upper tiles write zeros (no memset needed).
// Register-prefetch of next chunk overlaps global latency with compute.
// AB = [512][1536] fp32, AI at +0 (b1 folded), BJ at +768.
// ---------------------------------------------------------------------------
__global__ __launch_bounds__(256) void k_pair(
    const float* __restrict__ AB, const float* __restrict__ W2,
    const float* __restrict__ b2, float* __restrict__ pair)
{
    const int tid = threadIdx.x;
    const int bx = blockIdx.x & 7, by = blockIdx.x >> 3;
    const int bz = blockIdx.y;

    const int tx = tid & 15, ty = tid >> 4;
    const int i = by * 16 + ty, j = bx * 16 + tx;
    float* outp = pair + ((size_t)bz * NSPAN + i) * NSPAN + j;

    if (bx > by) { *outp = 0.f; return; }   // strictly-upper tile: all zero

    __shared__ __align__(16) float Ais[16][68];
    __shared__ __align__(16) float Bjs[16][68];
    __shared__ __align__(16) float w2s[768];
    for (int q = tid; q < 768; q += 256) w2s[q] = W2[q];

    const int sr = tid >> 4, sc = (tid & 15) << 2;
    const float* aSrc = AB + ((size_t)bz*NSPAN + by*16 + sr)*1536 + sc;
    const float* bSrc = AB + ((size_t)bz*NSPAN + bx*16 + sr)*1536 + 768 + sc;
    float acc = 0.f;

    float4 ra = *(const float4*)(aSrc);
    float4 rb = *(const float4*)(bSrc);

    for (int ch = 0; ch < 12; ++ch) {
        __syncthreads();
        *(float4*)&Ais[sr][sc] = ra;
        *(float4*)&Bjs[sr][sc] = rb;
        __syncthreads();
        if (ch < 11) {                       // next-chunk loads hide under FMAs
            ra = *(const float4*)(aSrc + (ch+1)*64);
            rb = *(const float4*)(bSrc + (ch+1)*64);
        }
        #pragma unroll
        for (int hq = 0; hq < 16; ++hq) {
            float4 a = *(const float4*)&Ais[ty][hq << 2];
            float4 b = *(const float4*)&Bjs[tx][hq << 2];
            float4 wv = *(const float4*)&w2s[ch*64 + (hq << 2)];
            acc = fmaf(fmaxf(a.x + b.x, 0.f), wv.x, acc);
            acc = fmaf(fmaxf(a.y + b.y, 0.f), wv.y, acc);
            acc = fmaf(fmaxf(a.z + b.z, 0.f), wv.z, acc);
            acc = fmaf(fmaxf(a.w + b.w, 0.f), wv.w, acc);
        }
    }
    *outp = (j < i) ? (acc + b2[0]) : 0.f;
}

// ---------------------------------------------------------------------------
extern "C" void kernel_launch(void* const* d_in, const int* in_sizes, int n_in,
                              void* d_out, int out_size, void* d_ws, size_t ws_size,
                              hipStream_t stream)
{
    const float* seq    = (const float*)d_in[0];
    const int*   starts = (const int*)  d_in[1];
    const int*   ends   = (const int*)  d_in[2];
    const float* Ws     = (const float*)d_in[3];
    const float* bs     = (const float*)d_in[4];
    const float* We     = (const float*)d_in[5];
    const float* be     = (const float*)d_in[6];
    const float* wemb   = (const float*)d_in[7];
    const float* Wout   = (const float*)d_in[8];
    const float* bout   = (const float*)d_in[9];
    const float* Wm     = (const float*)d_in[10];
    const float* bment  = (const float*)d_in[11];
    const float* W1     = (const float*)d_in[12];
    const float* b1     = (const float*)d_in[13];
    const float* W2     = (const float*)d_in[14];
    const float* b2     = (const float*)d_in[15];

    float* ws = (float*)d_ws;
    float* AB    = ws;                          // 512*1536 fp32
    short* Xg    = (short*)(ws + 786432);       // 1024*768 bf16
    short* Xcat  = (short*)(ws + 1179648);      // 512*1600 bf16
    short* SR    = (short*)(ws + 1589248);      // 512*768  bf16
    short* WtSE  = (short*)(ws + 1785856);      // 1536*768 bf16
    short* WtAB  = (short*)(ws + 2375680);      // 1536*768 bf16
    short* WtOut = (short*)(ws + 2965504);      // 768*1600 bf16

    float* out_mention = (float*)d_out;         // 512
    float* out_pair    = (float*)d_out + 512;   // 4*128*128

    hipLaunchKernelGGL(k_prep, dim3(3888), dim3(256), 0, stream,
                       seq, starts, ends, Ws, We, W1, Wout, wemb,
                       WtSE, WtAB, WtOut, Xg, Xcat);
    hipLaunchKernelGGL(k_g1, dim3(16, 24), dim3(128), 0, stream,
                       Xg, WtSE, bs, be, Xcat);
    hipLaunchKernelGGL(k_g2, dim3(16, 12), dim3(128), 0, stream,
                       Xcat, WtOut, bout, SR);
    hipLaunchKernelGGL(k_g3, dim3(16, 25), dim3(128), 0, stream,
                       SR, WtAB, b1, Wm, bment, AB, out_mention);
    hipLaunchKernelGGL(k_pair, dim3(64, 4), dim3(256), 0, stream,
                       AB, W2, b2, out_pair);
}